// Round 2
// baseline (506.945 us; speedup 1.0000x reference)
//
#include <hip/hip_runtime.h>
#include <hip/hip_bf16.h>
#include <math.h>

#define BDIM 2
#define NDIM 512
#define HID 768
#define BIAF 256
#define CLS 14
#define DD 257   // BIAF+1
#define NPOS 30
#define SDIM 25
#define HSZ 539  // 2*257+25

__device__ inline float bf2f(unsigned short u) {
    union { unsigned int i; float f; } c; c.i = ((unsigned)u) << 16; return c.f;
}
__device__ inline unsigned short f2bf(float f) {
    __hip_bfloat16 h = __float2bfloat16(f);
    return *(unsigned short*)&h;
}

template<typename T> __device__ inline float ldT(const T* p);
template<> __device__ inline float ldT<float>(const float* p) { return *p; }
template<> __device__ inline float ldT<unsigned short>(const unsigned short* p) { return bf2f(*p); }

template<typename T> __device__ inline float4 ld4(const T* p, int i4);
template<> __device__ inline float4 ld4<float>(const float* p, int i4) {
    return ((const float4*)p)[i4];
}
template<> __device__ inline float4 ld4<unsigned short>(const unsigned short* p, int i4) {
    ushort4 u = ((const ushort4*)p)[i4];
    return make_float4(bf2f(u.x), bf2f(u.y), bf2f(u.z), bf2f(u.w));
}

// ---------------------------------------------------------------------------
// detect: interpret first 8192 ushorts of x as bf16. If x is really f32,
// half of those are mantissa-junk with uniform-random exponent bytes -> max
// blows past 1e3 (or NaN). If really bf16, all are N(0,1) draws, max ~4.
// flag = 1 -> buffers are bf16; flag = 0 -> buffers are f32.
// ---------------------------------------------------------------------------
__global__ void detect_dtype(const unsigned short* __restrict__ x, int* __restrict__ flag) {
    __shared__ float red[256];
    float mx = 0.f;
    for (int i = threadIdx.x; i < 8192; i += 256) {
        float v = bf2f(x[i]);
        if (v != v) v = 1e30f;          // NaN -> huge
        mx = fmaxf(mx, fabsf(v));       // +-Inf stays Inf
    }
    red[threadIdx.x] = mx;
    __syncthreads();
    for (int s = 128; s > 0; s >>= 1) {
        if (threadIdx.x < s) red[threadIdx.x] = fmaxf(red[threadIdx.x], red[threadIdx.x + s]);
        __syncthreads();
    }
    if (threadIdx.x == 0) *flag = (red[0] < 1000.0f) ? 1 : 0;
}

// ---------------------------------------------------------------------------
// stage1 body (templated on input dtype)
// ---------------------------------------------------------------------------
template<typename T>
__device__ void stage1_body(
    const T* __restrict__ x, const T* __restrict__ y,
    const T* __restrict__ m1w, const T* __restrict__ m1b,
    const T* __restrict__ m2w, const T* __restrict__ m2b,
    const T* __restrict__ hw,  const T* __restrict__ hb,
    const T* __restrict__ tw,  const T* __restrict__ tb,
    const T* __restrict__ W,
    float* __restrict__ h1, float* __restrict__ tT,
    float* __restrict__ hk, float* __restrict__ tk,
    float (*xs)[HID], float (*ys)[HID], float (*hdv)[BIAF], float (*tlv)[BIAF])
{
    const int tid = threadIdx.x;
    const int b  = blockIdx.x / (NDIM/4);
    const int m0 = (blockIdx.x % (NDIM/4)) * 4;

    for (int t = tid; t < 4*HID; t += 256) {
        int mm = t / HID, r = t % HID;
        xs[mm][r] = ldT(x + (size_t)(b*NDIM + m0+mm)*HID + r);
        ys[mm][r] = ldT(y + (size_t)(b*NDIM + m0+mm)*HID + r);
    }
    __syncthreads();

    const int i = tid; // output feature 0..255
    float ha[4] = {0,0,0,0}, ta[4] = {0,0,0,0}, da[4] = {0,0,0,0}, la[4] = {0,0,0,0};
    const T* w1 = m1w + (size_t)i*HID;
    const T* w2 = m2w + (size_t)i*HID;
    const T* w3 = hw  + (size_t)i*HID;
    const T* w4 = tw  + (size_t)i*HID;
    for (int r4 = 0; r4 < HID/4; ++r4) {
        float4 f1 = ld4(w1, r4), f2 = ld4(w2, r4), f3 = ld4(w3, r4), f4 = ld4(w4, r4);
        #pragma unroll
        for (int mm = 0; mm < 4; ++mm) {
            float4 xv = *(const float4*)&xs[mm][r4*4];
            float4 yv = *(const float4*)&ys[mm][r4*4];
            ha[mm] += xv.x*f1.x + xv.y*f1.y + xv.z*f1.z + xv.w*f1.w;
            ta[mm] += yv.x*f2.x + yv.y*f2.y + yv.z*f2.z + yv.w*f2.w;
            da[mm] += xv.x*f3.x + xv.y*f3.y + xv.z*f3.z + xv.w*f3.w;
            la[mm] += xv.x*f4.x + xv.y*f4.y + xv.z*f4.z + xv.w*f4.w;
        }
    }
    const float b1 = ldT(m1b + i), b2 = ldT(m2b + i), b3 = ldT(hb + i), b4 = ldT(tb + i);
    #pragma unroll
    for (int mm = 0; mm < 4; ++mm) {
        float v = ha[mm] + b1;
        h1[(size_t)(b*NDIM + m0+mm)*DD + i] = 0.5f*v*(1.0f + erff(v*0.70710678118654752f));
        float u = ta[mm] + b2;
        tT[(size_t)(b*DD + i)*NDIM + (m0+mm)] = 0.5f*u*(1.0f + erff(u*0.70710678118654752f));
        float hv = da[mm] + b3; hdv[mm][i] = hv >= 0.f ? hv : 0.01f*hv;
        float tv = la[mm] + b4; tlv[mm][i] = tv >= 0.f ? tv : 0.01f*tv;
    }
    if (tid < 4) {
        h1[(size_t)(b*NDIM + m0+tid)*DD + BIAF] = 1.0f;
        tT[(size_t)(b*DD + BIAF)*NDIM + (m0+tid)] = 1.0f;
    }
    __syncthreads();
    if (tid < 4*CLS) { // hk
        int mm = tid / CLS, k = tid % CLS;
        float acc = 0.f;
        for (int ii = 0; ii < BIAF; ++ii) acc += hdv[mm][ii] * ldT(W + k*HSZ + ii);
        acc += ldT(W + k*HSZ + BIAF);
        hk[(size_t)(b*CLS + k)*NDIM + (m0+mm)] = acc;
    } else if (tid >= 64 && tid < 64 + 4*CLS) { // tk
        int t2 = tid - 64; int mm = t2 / CLS, k = t2 % CLS;
        float acc = 0.f;
        for (int ii = 0; ii < BIAF; ++ii) acc += tlv[mm][ii] * ldT(W + k*HSZ + DD + ii);
        acc += ldT(W + k*HSZ + DD + BIAF);
        tk[(size_t)(b*CLS + k)*NDIM + (m0+mm)] = acc;
    }
}

__global__ __launch_bounds__(256) void stage1(
    const void* x, const void* y,
    const void* m1w, const void* m1b, const void* m2w, const void* m2b,
    const void* hw, const void* hb, const void* tw, const void* tb,
    const void* W, const int* __restrict__ flag,
    float* __restrict__ h1, float* __restrict__ tT,
    float* __restrict__ hk, float* __restrict__ tk)
{
    __shared__ float xs[4][HID];
    __shared__ float ys[4][HID];
    __shared__ float hdv[4][BIAF];
    __shared__ float tlv[4][BIAF];
    if (*flag) {
        stage1_body<unsigned short>(
            (const unsigned short*)x, (const unsigned short*)y,
            (const unsigned short*)m1w, (const unsigned short*)m1b,
            (const unsigned short*)m2w, (const unsigned short*)m2b,
            (const unsigned short*)hw, (const unsigned short*)hb,
            (const unsigned short*)tw, (const unsigned short*)tb,
            (const unsigned short*)W, h1, tT, hk, tk, xs, ys, hdv, tlv);
    } else {
        stage1_body<float>(
            (const float*)x, (const float*)y,
            (const float*)m1w, (const float*)m1b,
            (const float*)m2w, (const float*)m2b,
            (const float*)hw, (const float*)hb,
            (const float*)tw, (const float*)tb,
            (const float*)W, h1, tT, hk, tk, xs, ys, hdv, tlv);
    }
}

// ---------------------------------------------------------------------------
// sk[k][d] = sum_h size_emb[d][h] * Ws[k][h]
// ---------------------------------------------------------------------------
template<typename T>
__device__ void sk_body(const T* __restrict__ semb, const T* __restrict__ W,
                        float* __restrict__ sk)
{
    int idx = blockIdx.x * 256 + threadIdx.x;
    if (idx < CLS * NPOS) {
        int k = idx / NPOS, d = idx % NPOS;
        float acc = 0.f;
        for (int h = 0; h < SDIM; ++h)
            acc += ldT(semb + d*SDIM + h) * ldT(W + k*HSZ + 2*DD + h);
        sk[idx] = acc;
    }
}

__global__ void sk_kernel(const void* semb, const void* W,
                          const int* __restrict__ flag, float* __restrict__ sk)
{
    if (*flag) sk_body<unsigned short>((const unsigned short*)semb, (const unsigned short*)W, sk);
    else       sk_body<float>((const float*)semb, (const float*)W, sk);
}

// ---------------------------------------------------------------------------
// gemm_biaf: A[b][k][m][j] = sum_i h1[b][m][i] * biaf_W[k][i][j]
// ---------------------------------------------------------------------------
template<typename T>
__device__ void gemm_biaf_body(
    const float* __restrict__ h1, const T* __restrict__ biafW, float* __restrict__ A,
    float (*Ls)[36], float (*Rs)[128])
{
    const int tid = threadIdx.x;
    const int tx = tid % 32, ty = tid / 32;
    const int j0 = blockIdx.x * 128;
    const int m0 = blockIdx.y * 32;
    const int bk = blockIdx.z, b = bk / CLS, k = bk % CLS;
    const float* L = h1 + (size_t)(b*NDIM + m0) * DD;
    const T* R = biafW + (size_t)k * DD * DD;
    float acc[4][4] = {};
    for (int k0 = 0; k0 < DD; k0 += 32) {
        for (int t = tid; t < 32*32; t += 256) {
            int mm = t / 32, kk = t % 32;
            Ls[kk][mm] = (k0 + kk < DD) ? L[(size_t)mm*DD + k0 + kk] : 0.f;
        }
        for (int t = tid; t < 32*128; t += 256) {
            int kk = t / 128, c = t % 128;
            int kg = k0 + kk, jg = j0 + c;
            Rs[kk][c] = (kg < DD && jg < DD) ? ldT(R + (size_t)kg*DD + jg) : 0.f;
        }
        __syncthreads();
        #pragma unroll 8
        for (int kk = 0; kk < 32; ++kk) {
            float4 a  = *(const float4*)&Ls[kk][ty*4];
            float4 bb = *(const float4*)&Rs[kk][tx*4];
            float av[4] = {a.x, a.y, a.z, a.w};
            float bv[4] = {bb.x, bb.y, bb.z, bb.w};
            #pragma unroll
            for (int im = 0; im < 4; ++im)
                #pragma unroll
                for (int jn = 0; jn < 4; ++jn)
                    acc[im][jn] += av[im] * bv[jn];
        }
        __syncthreads();
    }
    float* Ab = A + ((size_t)(b*CLS + k)*NDIM) * DD;
    #pragma unroll
    for (int im = 0; im < 4; ++im) {
        int m = m0 + ty*4 + im;
        #pragma unroll
        for (int jn = 0; jn < 4; ++jn) {
            int j = j0 + tx*4 + jn;
            if (j < DD) Ab[(size_t)m*DD + j] = acc[im][jn];
        }
    }
}

__global__ __launch_bounds__(256) void gemm_biaf(
    const float* __restrict__ h1, const void* biafW,
    const int* __restrict__ flag, float* __restrict__ A)
{
    __shared__ float Ls[32][36];
    __shared__ float Rs[32][128];
    if (*flag) gemm_biaf_body<unsigned short>(h1, (const unsigned short*)biafW, A, Ls, Rs);
    else       gemm_biaf_body<float>(h1, (const float*)biafW, A, Ls, Rs);
}

// ---------------------------------------------------------------------------
// gemm_out: out[b][k][m][n] = sum_j A[b][k][m][j] * tT[b][j][n]
//                             + hk[b][k][m] + tk[b][k][n] + sk[k][clip(n-m)]
// ---------------------------------------------------------------------------
__global__ __launch_bounds__(256) void gemm_out(
    const float* __restrict__ A,
    const float* __restrict__ tT,
    const float* __restrict__ hk,
    const float* __restrict__ tk,
    const float* __restrict__ sk,
    const int* __restrict__ flag,
    void* __restrict__ out)
{
    __shared__ float Ls[32][36];
    __shared__ float Rs[32][128];
    __shared__ float skr[NPOS];
    const int tid = threadIdx.x;
    const int tx = tid % 32, ty = tid / 32;
    const int n0 = blockIdx.x * 128;
    const int m0 = blockIdx.y * 32;
    const int bk = blockIdx.z, b = bk / CLS, k = bk % CLS;
    const int isbf = *flag;
    if (tid < NPOS) skr[tid] = sk[k*NPOS + tid];
    const float* L = A + ((size_t)(b*CLS + k)*NDIM + m0) * DD;
    const float* R = tT + (size_t)b * DD * NDIM + n0;
    float acc[4][4] = {};
    for (int k0 = 0; k0 < DD; k0 += 32) {
        for (int t = tid; t < 32*32; t += 256) {
            int mm = t / 32, kk = t % 32;
            Ls[kk][mm] = (k0 + kk < DD) ? L[(size_t)mm*DD + k0 + kk] : 0.f;
        }
        for (int t = tid; t < 32*128; t += 256) {
            int kk = t / 128, c = t % 128;
            Rs[kk][c] = (k0 + kk < DD) ? R[(size_t)(k0+kk)*NDIM + c] : 0.f;
        }
        __syncthreads();
        #pragma unroll 8
        for (int kk = 0; kk < 32; ++kk) {
            float4 a  = *(const float4*)&Ls[kk][ty*4];
            float4 bb = *(const float4*)&Rs[kk][tx*4];
            float av[4] = {a.x, a.y, a.z, a.w};
            float bv[4] = {bb.x, bb.y, bb.z, bb.w};
            #pragma unroll
            for (int im = 0; im < 4; ++im)
                #pragma unroll
                for (int jn = 0; jn < 4; ++jn)
                    acc[im][jn] += av[im] * bv[jn];
        }
        __syncthreads();
    }
    const int base = (b*CLS + k)*NDIM;
    float hkv[4], tkv[4];
    #pragma unroll
    for (int im = 0; im < 4; ++im) hkv[im] = hk[(size_t)base + m0 + ty*4 + im];
    #pragma unroll
    for (int jn = 0; jn < 4; ++jn) tkv[jn] = tk[(size_t)base + n0 + tx*4 + jn];
    #pragma unroll
    for (int im = 0; im < 4; ++im) {
        int m = m0 + ty*4 + im;
        float vals[4];
        #pragma unroll
        for (int jn = 0; jn < 4; ++jn) {
            int n = n0 + tx*4 + jn;
            int d = n - m; d = d < -15 ? -15 : (d > 14 ? 14 : d); d += 15;
            vals[jn] = acc[im][jn] + hkv[im] + tkv[jn] + skr[d];
        }
        size_t idx = ((size_t)base + m)*NDIM + n0 + tx*4;
        if (isbf) {
            union { ushort4 u4; unsigned short s[4]; } pk;
            #pragma unroll
            for (int jn = 0; jn < 4; ++jn) pk.s[jn] = f2bf(vals[jn]);
            *(ushort4*)&((unsigned short*)out)[idx] = pk.u4;
        } else {
            float4 v4 = make_float4(vals[0], vals[1], vals[2], vals[3]);
            *(float4*)&((float*)out)[idx] = v4;
        }
    }
}

// ---------------------------------------------------------------------------
extern "C" void kernel_launch(void* const* d_in, const int* in_sizes, int n_in,
                              void* d_out, int out_size, void* d_ws, size_t ws_size,
                              hipStream_t stream) {
    const void* x    = d_in[0];
    const void* y    = d_in[1];
    // d_in[2] = z : unused by the reference
    const void* m1w  = d_in[3];
    const void* m1b  = d_in[4];
    const void* m2w  = d_in[5];
    const void* m2b  = d_in[6];
    const void* hw   = d_in[7];
    const void* hb   = d_in[8];
    const void* tw   = d_in[9];
    const void* tb   = d_in[10];
    const void* biafW= d_in[11];
    const void* W    = d_in[12];
    const void* semb = d_in[13];

    // workspace layout: [flag(4 floats pad)] then float buffers, total ~17 MB
    int*   flag = (int*)d_ws;
    float* ws   = (float*)d_ws + 4;
    float* h1  = ws;                                  // B*N*D      = 263168
    float* tT  = h1 + (size_t)BDIM*NDIM*DD;           // B*D*N      = 263168
    float* hkp = tT + (size_t)BDIM*DD*NDIM;           // B*CLS*N    = 14336
    float* tkp = hkp + (size_t)BDIM*CLS*NDIM;         // B*CLS*N    = 14336
    float* skp = tkp + (size_t)BDIM*CLS*NDIM;         // CLS*NPOS   = 420
    float* Ap  = skp + 428;                           // B*CLS*N*D  = 3687424 (16B-aligned)

    detect_dtype<<<1, 256, 0, stream>>>((const unsigned short*)x, flag);
    stage1<<<BDIM*(NDIM/4), 256, 0, stream>>>(x, y, m1w, m1b, m2w, m2b,
                                              hw, hb, tw, tb, W, flag, h1, tT, hkp, tkp);
    sk_kernel<<<2, 256, 0, stream>>>(semb, W, flag, skp);
    gemm_biaf<<<dim3(3, NDIM/32, BDIM*CLS), 256, 0, stream>>>(h1, biafW, flag, Ap);
    gemm_out<<<dim3(NDIM/128, NDIM/32, BDIM*CLS), 256, 0, stream>>>(Ap, tT, hkp, tkp, skp, flag,
                                                                    (unsigned short*)d_out);
}